// Round 8
// baseline (791.758 us; speedup 1.0000x reference)
//
#include <hip/hip_runtime.h>
#include <hip/hip_bf16.h>
#include <math.h>

typedef __hip_bfloat16 bf16;
typedef __attribute__((ext_vector_type(8))) short short8;   // 8 x bf16 MFMA frag
typedef __attribute__((ext_vector_type(4))) float floatx4;  // 4 x f32 MFMA acc

// Problem constants: B=64, DIM=256, HID=512, NH=4, KD=16, D=64, 28x28, WH=7
#define BB    64
#define DIMC  256
#define HIDC  512
#define NHH   4
#define HH_   28
#define WW_   28
#define PP    784   // 28*28

__device__ __forceinline__ float toF(bf16 x) { return __bfloat162float(x); }
__device__ __forceinline__ unsigned short f2bits(float f) {
    union { bf16 h; unsigned short u; } cv; cv.h = __float2bfloat16(f); return cv.u;
}
__device__ __forceinline__ float bits2f(unsigned short u) {
    union { unsigned int u32; float f; } cv; cv.u32 = ((unsigned int)u) << 16; return cv.f;
}

// ---------------------------------------------------------------------------
// fp32 -> bf16 weight convert
// ---------------------------------------------------------------------------
__global__ __launch_bounds__(256) void cvt_f2b(
    const float* __restrict__ s, bf16* __restrict__ d, int n)
{
    int i = blockIdx.x * 256 + threadIdx.x;
    if (i < n) d[i] = __float2bfloat16(s[i]);
}

// ---------------------------------------------------------------------------
// fp32 NCHW [64][256][784] -> bf16 NHWC [64][784][256] (LDS 32x32 transpose)
// grid (25, 8, 64), block 256
// ---------------------------------------------------------------------------
__global__ __launch_bounds__(256) void tr_cvt(
    const float* __restrict__ in, bf16* __restrict__ out)
{
    __shared__ float t[32][33];
    int n  = blockIdx.z;
    int p0 = blockIdx.x * 32;
    int c0 = blockIdx.y * 32;
    int tx = threadIdx.x & 31;
    int ty = threadIdx.x >> 5;   // 0..7
#pragma unroll
    for (int e = 0; e < 4; e++) {
        int c = c0 + ty + e * 8;
        int p = p0 + tx;
        if (p < PP) t[ty + e * 8][tx] = in[((size_t)n * DIMC + c) * PP + p];
    }
    __syncthreads();
#pragma unroll
    for (int e = 0; e < 4; e++) {
        int p = p0 + ty + e * 8;
        int c = c0 + tx;
        if (p < PP) out[((size_t)n * PP + p) * DIMC + c] = __float2bfloat16(t[tx][ty + e * 8]);
    }
}

// ---------------------------------------------------------------------------
// Depthwise 3x3 conv + BN + residual (NCHW fp32) — proven (round 3)
// ---------------------------------------------------------------------------
__global__ __launch_bounds__(256) void dw3x3_kernel(
    const float* __restrict__ in, const float* __restrict__ w,
    const float* __restrict__ s, const float* __restrict__ b,
    float* __restrict__ out)
{
    int nc = blockIdx.x;
    int c  = nc & (DIMC - 1);
    const float* ip = in + (size_t)nc * PP;
    float*       op = out + (size_t)nc * PP;
    float w9[9];
#pragma unroll
    for (int i = 0; i < 9; i++) w9[i] = w[c * 9 + i];
    float sc = s[c], bb = b[c];
    for (int p = threadIdx.x; p < PP; p += 256) {
        int h = p / WW_, x = p % WW_;
        float acc = 0.f;
#pragma unroll
        for (int i = 0; i < 3; i++) {
            int hh = h + i - 1;
            if (hh < 0 || hh >= HH_) continue;
#pragma unroll
            for (int j = 0; j < 3; j++) {
                int xx = x + j - 1;
                if (xx < 0 || xx >= WW_) continue;
                acc += w9[i * 3 + j] * ip[hh * WW_ + xx];
            }
        }
        op[p] = ip[p] + acc * sc + bb;
    }
}

// ---------------------------------------------------------------------------
// Per-head depthwise 5x5 + BN on q channels, NHWC bf16 in/out.
// grid (196, 64), block 256 = (p-sub 0..3) x (hk 0..63); coalesced both sides.
// qkv NHWC channel of head hh, kc -> hh*96+kc ; Q NHWC channel hk = hh*16+kc.
// ---------------------------------------------------------------------------
__global__ __launch_bounds__(256) void dws5x5_nhwc(
    const bf16* __restrict__ qkv,   // [64][784][384]
    const float* __restrict__ w,    // [64][25]  (hk-major)
    const float* __restrict__ s, const float* __restrict__ b,
    bf16* __restrict__ qout)        // [64][784][64]
{
    int n  = blockIdx.y;
    int p  = blockIdx.x * 4 + (threadIdx.x >> 6);
    int hk = threadIdx.x & 63;
    int hh = hk >> 4, kc = hk & 15;
    int cin = hh * 96 + kc;
    int h = p / 28, x = p % 28;
    float w25[25];
#pragma unroll
    for (int i = 0; i < 25; i++) w25[i] = w[hk * 25 + i];
    float acc = 0.f;
#pragma unroll
    for (int i = 0; i < 5; i++) {
        int h2 = h + i - 2;
        if (h2 < 0 || h2 >= HH_) continue;
#pragma unroll
        for (int j = 0; j < 5; j++) {
            int x2 = x + j - 2;
            if (x2 < 0 || x2 >= WW_) continue;
            acc += w25[i * 5 + j] * toF(qkv[((size_t)n * PP + h2 * 28 + x2) * 384 + cin]);
        }
    }
    qout[((size_t)n * PP + p) * 64 + hk] = __float2bfloat16(acc * s[hk] + b[hk]);
}

// ---------------------------------------------------------------------------
// 1x1 conv as bf16 MFMA GEMM, NHWC bf16 input:
//   out[n,co,p] = sum_ci W[co,ci] * X[n,p,ci]
// Tile 64(co) x 112(p), K-step 32, 4 waves. Staging: ONE uint4 (8 k at one p)
// per task, b128 LDS write at pitch 40 (conflict-free, proven r6/r7 path).
// OUTMODE: 0 = bf16 NHWC; 1 = fp32 NCHW; 2 = both.   grid (7, M/64, 64)
// ---------------------------------------------------------------------------
template <bool RELU, bool RES, int OUTMODE>
__global__ __launch_bounds__(256) void gemm_mfma(
    const bf16* __restrict__ Wb,    // [M][K] bf16
    const bf16* __restrict__ X,     // [64][784][K] bf16 NHWC
    const float* __restrict__ S, const float* __restrict__ Bb,
    const float* __restrict__ res,  // [64][M][784] fp32 NCHW (if RES)
    float* __restrict__ outF,       // fp32 NCHW (OUTMODE 1/2)
    bf16*  __restrict__ outB,       // bf16 NHWC (OUTMODE 0/2)
    int M, int K)
{
    int n    = blockIdx.z;
    int co0  = blockIdx.y * 64;
    int p0   = blockIdx.x * 112;
    int tid  = threadIdx.x;
    int wv   = tid >> 6;
    int ln   = tid & 63;
    int l15  = ln & 15;
    int quad = ln >> 4;

    __shared__ __align__(16) unsigned short Blds[112 * 40];  // [pp][kk], pitch 40

    floatx4 acc[7];
#pragma unroll
    for (int t = 0; t < 7; t++) acc[t] = (floatx4){0.f, 0.f, 0.f, 0.f};

    const bf16* Arow = Wb + (size_t)(co0 + wv * 16 + l15) * K + quad * 8;
    const unsigned short* Xb = (const unsigned short*)X + ((size_t)n * PP + p0) * K;

    // 448 tasks = 112 pp x 4 granules; idx = pp*4 + G (64B-contiguous per 4 lanes)
    int pp_a = tid >> 2, G_a = tid & 3;                 // pp_a in [0,64)
    int idx_b = tid + 256;
    int pp_b = idx_b >> 2, G_b = idx_b & 3;             // pp_b in [64,128), valid < 112

    for (int k0 = 0; k0 < K; k0 += 32) {
        {
            uint4 v = *(const uint4*)(Xb + (size_t)pp_a * K + k0 + G_a * 8);
            *(uint4*)&Blds[pp_a * 40 + G_a * 8] = v;
        }
        if (idx_b < 448) {
            uint4 v = *(const uint4*)(Xb + (size_t)pp_b * K + k0 + G_b * 8);
            *(uint4*)&Blds[pp_b * 40 + G_b * 8] = v;
        }
        short8 afrag = *(const short8*)(Arow + k0);
        __syncthreads();
#pragma unroll
        for (int t = 0; t < 7; t++) {
            short8 bfrag = *(const short8*)&Blds[(t * 16 + l15) * 40 + quad * 8];
            acc[t] = __builtin_amdgcn_mfma_f32_16x16x32_bf16(afrag, bfrag, acc[t], 0, 0, 0);
        }
        __syncthreads();
    }

    // epilogue: lane holds C[co = co0+wv*16+quad*4+r][p = p0+t*16+l15]
    int cobase = co0 + wv * 16 + quad * 4;
    float s4[4], b4[4];
#pragma unroll
    for (int r = 0; r < 4; r++) { s4[r] = S[cobase + r]; b4[r] = Bb[cobase + r]; }

#pragma unroll
    for (int t = 0; t < 7; t++) {
        int p = p0 + t * 16 + l15;   // always < 784
        float y[4];
#pragma unroll
        for (int r = 0; r < 4; r++) {
            y[r] = acc[t][r] * s4[r] + b4[r];
            if (RELU) y[r] = fmaxf(y[r], 0.f);
            if (RES) y[r] += res[((size_t)n * M + cobase + r) * PP + p];
        }
        if (OUTMODE == 1 || OUTMODE == 2) {
#pragma unroll
            for (int r = 0; r < 4; r++)
                outF[((size_t)n * M + cobase + r) * PP + p] = y[r];
        }
        if (OUTMODE == 0 || OUTMODE == 2) {
            union { unsigned short h4[4]; uint2 u; } pk;
#pragma unroll
            for (int r = 0; r < 4; r++) pk.h4[r] = f2bits(y[r]);
            *(uint2*)((unsigned short*)outB + ((size_t)n * PP + p) * M + cobase) = pk.u;
        }
    }
}

// ---------------------------------------------------------------------------
// 7x7 window attention, NHWC bf16 I/O. Block per (n, head, win-row, col-pair).
// grid (8, 4, 64). Covers 2 windows: lp = r*14 + c, global p = pbase+r*28+c.
// Same proven compute core as r7; global loads/stores re-indexed for NHWC
// (channel-inner => fully coalesced), PV inner loop now conflict-free:
// srow is wave-broadcast, vL reads are 32 consecutive dwords (all banks).
// ---------------------------------------------------------------------------
__global__ __launch_bounds__(256) void attn_kernel(
    const bf16*  __restrict__ Q,       // [64][784][64] NHWC (hk = hh*16+kc)
    const bf16*  __restrict__ KV,      // [64][784][384] NHWC
    const float* __restrict__ pos,     // [4][49][49]
    bf16* __restrict__ O)              // [64][784][256] NHWC (c = hh*64+d)
{
    int wjp = blockIdx.x & 1, wi = blockIdx.x >> 1;
    int hh  = blockIdx.y, n = blockIdx.z;
    int tid = threadIdx.x;
    int pbase = wi * 7 * 28 + wjp * 14;

    __shared__ __align__(16) unsigned short qL[16 * 98];   // [kc][lp]
    __shared__ __align__(16) unsigned short kL[16 * 98];
    __shared__ __align__(16) unsigned short vL[98 * 66];   // [lp][d] pitch 66
    __shared__ float sL[98 * 51];                          // [w*49+qi][ki] pitch 51

    const unsigned short* KVu = (const unsigned short*)KV;
    const unsigned short* Qu  = (const unsigned short*)Q;

    // ---- load q, k: idx = lp*16 + kc (16 contiguous channels per lp) ----
    for (int idx = tid; idx < 1568; idx += 256) {
        int lp = idx >> 4, kc = idx & 15;
        int p  = pbase + (lp / 14) * 28 + lp % 14;
        qL[kc * 98 + lp] = Qu[((size_t)n * PP + p) * 64 + hh * 16 + kc];
        kL[kc * 98 + lp] = KVu[((size_t)n * PP + p) * 384 + hh * 96 + 16 + kc];
    }
    // ---- load v: idx = lp*64 + d (64 contiguous channels = 128B) ----
    for (int idx = tid; idx < 6272; idx += 256) {
        int lp = idx >> 6, d = idx & 63;
        int p = pbase + (lp / 14) * 28 + lp % 14;
        vL[lp * 66 + d] = KVu[((size_t)n * PP + p) * 384 + hh * 96 + 32 + d];
    }
    __syncthreads();

    // ---- S = 0.25*q.k + pos  (2 windows x 49 x 49) ----
    for (int idx = tid; idx < 4802; idx += 256) {
        int w  = idx / 2401;
        int rm = idx - w * 2401;
        int qi = rm / 49, ki = rm - qi * 49;
        int lpq = (qi / 7) * 14 + w * 7 + qi % 7;
        int lpk = (ki / 7) * 14 + w * 7 + ki % 7;
        float acc = 0.f;
#pragma unroll
        for (int kc = 0; kc < 16; kc++)
            acc += bits2f(qL[kc * 98 + lpq]) * bits2f(kL[kc * 98 + lpk]);
        sL[(w * 49 + qi) * 51 + ki] = acc * 0.25f + pos[(hh * 49 + qi) * 49 + ki];
    }
    __syncthreads();

    // ---- softmax (one thread per row; 98 rows) ----
    if (tid < 98) {
        float* row = &sL[tid * 51];
        float m = row[0];
        for (int ki = 1; ki < 49; ki++) m = fmaxf(m, row[ki]);
        float sum = 0.f;
        for (int ki = 0; ki < 49; ki++) {
            float e = __expf(row[ki] - m);
            row[ki] = e;
            sum += e;
        }
        float inv = 1.f / sum;
        for (int ki = 0; ki < 49; ki++) row[ki] *= inv;
    }
    __syncthreads();

    // ---- O = relu(attn @ V): idx = lp*32 + d2 (channel pair 2*d2, 2*d2+1) ----
    unsigned short* Ou = (unsigned short*)O;
    for (int idx = tid; idx < 3136; idx += 256) {
        int lp = idx >> 5, d2 = idx & 31;
        int r = lp / 14, c = lp % 14;
        int w = c / 7, cc = c - w * 7;
        int qi = r * 7 + cc;
        const float* srow = &sL[(w * 49 + qi) * 51];   // broadcast across half-wave
        float a0 = 0.f, a1 = 0.f;
#pragma unroll
        for (int ki = 0; ki < 49; ki++) {
            int lpk = (ki / 7) * 14 + w * 7 + ki % 7;
            unsigned int v2 = *(const unsigned int*)&vL[lpk * 66 + d2 * 2];
            float sv = srow[ki];
            a0 += sv * bits2f((unsigned short)(v2 & 0xFFFF));
            a1 += sv * bits2f((unsigned short)(v2 >> 16));
        }
        int p = pbase + r * 28 + c;
        unsigned int o2 = (unsigned int)f2bits(fmaxf(a0, 0.f))
                        | ((unsigned int)f2bits(fmaxf(a1, 0.f)) << 16);
        *(unsigned int*)&Ou[((size_t)n * PP + p) * 256 + hh * 64 + d2 * 2] = o2;
    }
}

// ---------------------------------------------------------------------------
extern "C" void kernel_launch(void* const* d_in, const int* in_sizes, int n_in,
                              void* d_out, int out_size, void* d_ws, size_t ws_size,
                              hipStream_t stream)
{
    const float* x0     = (const float*)d_in[0];
    const float* dw0_w  = (const float*)d_in[1];
    const float* dw0_s  = (const float*)d_in[2];
    const float* dw0_b  = (const float*)d_in[3];
    const float* dw1_w  = (const float*)d_in[4];
    const float* dw1_s  = (const float*)d_in[5];
    const float* dw1_b  = (const float*)d_in[6];
    const float* f0w1   = (const float*)d_in[7];
    const float* f0s1   = (const float*)d_in[8];
    const float* f0b1   = (const float*)d_in[9];
    const float* f0w2   = (const float*)d_in[10];
    const float* f0s2   = (const float*)d_in[11];
    const float* f0b2   = (const float*)d_in[12];
    const float* f1w1   = (const float*)d_in[13];
    const float* f1s1   = (const float*)d_in[14];
    const float* f1b1   = (const float*)d_in[15];
    const float* f1w2   = (const float*)d_in[16];
    const float* f1s2   = (const float*)d_in[17];
    const float* f1b2   = (const float*)d_in[18];
    const float* qkv_w  = (const float*)d_in[19];
    const float* qkv_s  = (const float*)d_in[20];
    const float* qkv_b  = (const float*)d_in[21];
    const float* dws_w  = (const float*)d_in[22];
    const float* dws_s  = (const float*)d_in[23];
    const float* dws_b  = (const float*)d_in[24];
    const float* proj_w = (const float*)d_in[25];
    const float* proj_s = (const float*)d_in[26];
    const float* proj_b = (const float*)d_in[27];
    const float* pos    = (const float*)d_in[28];

    // -------- workspace (aliased, 181.2 MB; r1 layout proved >=193 MB usable) ----
    // X1   fp32 NCHW [64][256][784]  (residual stream; in-place updated)
    // Hb   bf16 NHWC [64][784][512]  | Qb bf16 NHWC [64][784][64] (alias, disjoint)
    // slotC: QKVb bf16 NHWC [64][784][384] -> X2 fp32 NCHW (disjoint in time)
    // X1b  bf16 NHWC [64][784][256]  (GEMM input mirror; reused for X2b)
    // Ob   bf16 NHWC [64][784][256] in d_out until final GEMM overwrites d_out.
    const size_t NXB = (size_t)BB * DIMC * PP * 4;    // 51,380,224 B
    char* base  = (char*)d_ws;
    float* X1   = (float*)base;
    bf16*  Hb   = (bf16*)(base + NXB);
    bf16*  Qb   = Hb;                                  // alias, disjoint in time
    char*  C_   = base + 2 * NXB;
    bf16*  QKVb = (bf16*)C_;
    float* X2   = (float*)C_;                          // alias, disjoint in time
    bf16*  X1b  = (bf16*)(base + 3 * NXB);             // 25.7 MB
    bf16*  Wc   = (bf16*)(base + 3 * NXB + NXB / 2);
    bf16*  Ob   = (bf16*)d_out;
    float* outp = (float*)d_out;

    bf16* Wf0w1 = Wc;                  // [512][256]
    bf16* Wf0w2 = Wf0w1 + 131072;      // [256][512]
    bf16* Wf1w1 = Wf0w2 + 131072;      // [512][256]
    bf16* Wf1w2 = Wf1w1 + 131072;      // [256][512]
    bf16* Wqkv  = Wf1w2 + 131072;      // [384][256]
    bf16* Wproj = Wqkv + 98304;        // [256][256]

    dim3 blk(256);

    // 0) weights fp32 -> bf16
    cvt_f2b<<<512, blk, 0, stream>>>(f0w1, Wf0w1, 131072);
    cvt_f2b<<<512, blk, 0, stream>>>(f0w2, Wf0w2, 131072);
    cvt_f2b<<<512, blk, 0, stream>>>(f1w1, Wf1w1, 131072);
    cvt_f2b<<<512, blk, 0, stream>>>(f1w2, Wf1w2, 131072);
    cvt_f2b<<<384, blk, 0, stream>>>(qkv_w, Wqkv, 98304);
    cvt_f2b<<<256, blk, 0, stream>>>(proj_w, Wproj, 65536);

    // 1) x = x + dw0(x); mirror to NHWC bf16
    dw3x3_kernel<<<BB * DIMC, blk, 0, stream>>>(x0, dw0_w, dw0_s, dw0_b, X1);
    tr_cvt<<<dim3(25, 8, BB), blk, 0, stream>>>(X1, X1b);

    // 2-3) ffn0 (ffn0-2 epilogue refreshes both X1 fp32 and X1b NHWC)
    gemm_mfma<true, false, 0><<<dim3(7, HIDC / 64, BB), blk, 0, stream>>>(
        Wf0w1, X1b, f0s1, f0b1, nullptr, nullptr, Hb, HIDC, DIMC);
    gemm_mfma<false, true, 2><<<dim3(7, DIMC / 64, BB), blk, 0, stream>>>(
        Wf0w2, Hb, f0s2, f0b2, X1, X1, X1b, DIMC, HIDC);

    // 4-7) attention
    gemm_mfma<false, false, 0><<<dim3(7, 384 / 64, BB), blk, 0, stream>>>(
        Wqkv, X1b, qkv_s, qkv_b, nullptr, nullptr, QKVb, 384, DIMC);
    dws5x5_nhwc<<<dim3(196, BB), blk, 0, stream>>>(QKVb, dws_w, dws_s, dws_b, Qb);
    attn_kernel<<<dim3(8, NHH, BB), blk, 0, stream>>>(Qb, QKVb, pos, Ob);
    gemm_mfma<false, true, 1><<<dim3(7, DIMC / 64, BB), blk, 0, stream>>>(
        Wproj, Ob, proj_s, proj_b, X1, X1, nullptr, DIMC, DIMC);

    // 8) x = x + dw1(x)  (QKVb dead -> X2); mirror to NHWC bf16 (reuse X1b)
    dw3x3_kernel<<<BB * DIMC, blk, 0, stream>>>(X1, dw1_w, dw1_s, dw1_b, X2);
    tr_cvt<<<dim3(25, 8, BB), blk, 0, stream>>>(X2, X1b);

    // 9-10) ffn1, final fp32 NCHW to d_out
    gemm_mfma<true, false, 0><<<dim3(7, HIDC / 64, BB), blk, 0, stream>>>(
        Wf1w1, X1b, f1s1, f1b1, nullptr, nullptr, Hb, HIDC, DIMC);
    gemm_mfma<false, true, 1><<<dim3(7, DIMC / 64, BB), blk, 0, stream>>>(
        Wf1w2, Hb, f1s2, f1b2, X2, outp, nullptr, DIMC, HIDC);
}